// Round 1
// baseline (385.496 us; speedup 1.0000x reference)
//
#include <hip/hip_runtime.h>
#include <hip/hip_bf16.h>
#include <math.h>

typedef __bf16 bf16x8 __attribute__((ext_vector_type(8)));
typedef float  f32x4  __attribute__((ext_vector_type(4)));

#define B_    2
#define N_    2048
#define H_    16
#define D_    64
#define HD    (H_ * D_)
#define QBLK  64
#define KVBLK 32
#define SCALE 0.125f

__global__ __launch_bounds__(256) void attn_fwd_kernel(
    const float* __restrict__ q,
    const float* __restrict__ k,
    const float* __restrict__ v,
    float* __restrict__ out)
{
    const int tid  = threadIdx.x;
    const int lane = tid & 63;
    const int w    = tid >> 6;     // wave id 0..3
    const int lo   = lane & 15;
    const int hi   = lane >> 4;
    const int qt   = blockIdx.x;   // q tile of 64 rows
    const int h    = blockIdx.y;
    const int b    = blockIdx.z;

    // per-wave P buffer; stride 40 bf16 (80 B) breaks power-of-2 banking
    __shared__ __align__(16) __bf16 p_lds[4][16][40];

    const size_t bh_off = (size_t)b * N_ * HD + (size_t)h * D_;
    const float* qp = q + bh_off;
    const float* kp = k + bh_off;
    const float* vp = v + bh_off;
    float*       op = out + bh_off;

    const int q0 = qt * QBLK + w * 16;   // this wave's first q row

    // ---- Q A-frags: lane holds Q[q0+lo][kk*32 + hi*8 + j], j=0..7 (scaled) ----
    bf16x8 qa[2];
    {
        const float* qrow = qp + (size_t)(q0 + lo) * HD + hi * 8;
        #pragma unroll
        for (int kk = 0; kk < 2; ++kk) {
            #pragma unroll
            for (int j = 0; j < 8; ++j)
                qa[kk][j] = (__bf16)(qrow[kk * 32 + j] * SCALE);
        }
    }

    float m[4], l[4];
    f32x4 o[4];
    #pragma unroll
    for (int r = 0; r < 4; ++r) { m[r] = -INFINITY; l[r] = 0.f; }
    #pragma unroll
    for (int f = 0; f < 4; ++f) o[f] = (f32x4)0.f;

    for (int kv0 = 0; kv0 < N_; kv0 += KVBLK) {
        // ---- QK^T: S[16 rows][32 cols] in two 16x16 C-frags ----
        f32x4 s[2];
        #pragma unroll
        for (int c = 0; c < 2; ++c) {
            s[c] = (f32x4)0.f;
            const float* krow = kp + (size_t)(kv0 + c * 16 + lo) * HD + hi * 8;
            #pragma unroll
            for (int kk = 0; kk < 2; ++kk) {
                bf16x8 kb;
                #pragma unroll
                for (int j = 0; j < 8; ++j)
                    kb[j] = (__bf16)krow[kk * 32 + j];
                s[c] = __builtin_amdgcn_mfma_f32_16x16x32_bf16(qa[kk], kb, s[c], 0, 0, 0);
            }
        }

        // ---- online softmax (row = hi*4 + r, cols spread over lo) ----
        float alpha[4], p0[4], p1[4];
        #pragma unroll
        for (int r = 0; r < 4; ++r) {
            float t = fmaxf(s[0][r], s[1][r]);
            #pragma unroll
            for (int msk = 1; msk <= 8; msk <<= 1)
                t = fmaxf(t, __shfl_xor(t, msk, 64));
            float mn = fmaxf(m[r], t);
            alpha[r] = __expf(m[r] - mn);
            p0[r] = __expf(s[0][r] - mn);
            p1[r] = __expf(s[1][r] - mn);
            float rs = p0[r] + p1[r];
            #pragma unroll
            for (int msk = 1; msk <= 8; msk <<= 1)
                rs += __shfl_xor(rs, msk, 64);
            l[r] = l[r] * alpha[r] + rs;
            m[r] = mn;
        }
        #pragma unroll
        for (int f = 0; f < 4; ++f)
            #pragma unroll
            for (int r = 0; r < 4; ++r)
                o[f][r] *= alpha[r];

        // ---- P: C-layout -> LDS -> A-layout ----
        #pragma unroll
        for (int r = 0; r < 4; ++r) {
            p_lds[w][hi * 4 + r][lo]      = (__bf16)p0[r];
            p_lds[w][hi * 4 + r][16 + lo] = (__bf16)p1[r];
        }
        __syncthreads();
        bf16x8 pa = *(const bf16x8*)&p_lds[w][lo][hi * 8];

        // ---- PV: O[16][64] += P[16][32] * V[32][64] ----
        #pragma unroll
        for (int f = 0; f < 4; ++f) {
            const float* vrow = vp + (size_t)(kv0 + hi * 8) * HD + f * 16 + lo;
            bf16x8 vb;
            #pragma unroll
            for (int j = 0; j < 8; ++j)
                vb[j] = (__bf16)vrow[(size_t)j * HD];
            o[f] = __builtin_amdgcn_mfma_f32_16x16x32_bf16(pa, vb, o[f], 0, 0, 0);
        }
        __syncthreads();
    }

    // ---- epilogue: out[b, q0+hi*4+r, h, f*16+lo] = o[f][r] / l[r] ----
    #pragma unroll
    for (int r = 0; r < 4; ++r) {
        float rinv = 1.f / l[r];
        float* orow = op + (size_t)(q0 + hi * 4 + r) * HD;
        #pragma unroll
        for (int f = 0; f < 4; ++f)
            orow[f * 16 + lo] = o[f][r] * rinv;
    }
}

extern "C" void kernel_launch(void* const* d_in, const int* in_sizes, int n_in,
                              void* d_out, int out_size, void* d_ws, size_t ws_size,
                              hipStream_t stream)
{
    const float* q = (const float*)d_in[0];
    const float* k = (const float*)d_in[1];
    const float* v = (const float*)d_in[2];
    float* out = (float*)d_out;

    dim3 grid(N_ / QBLK, H_, B_);
    dim3 block(256);
    attn_fwd_kernel<<<grid, block, 0, stream>>>(q, k, v, out);
}

// Round 3
// 211.734 us; speedup vs baseline: 1.8207x; 1.8207x over previous
//
#include <hip/hip_runtime.h>
#include <hip/hip_bf16.h>
#include <math.h>

typedef __bf16 bf16x8 __attribute__((ext_vector_type(8)));
typedef float  f32x4  __attribute__((ext_vector_type(4)));

#define B_    2
#define N_    2048
#define H_    16
#define D_    64
#define HD    (H_ * D_)
#define SCALE 0.125f
#define QBLK  128     // q rows per block (4 waves x 32)
#define KVBLK 64
#define CVT_SZ (8388608ull)  // B*N*H*D * 2 bytes

// ---------------- pass 1a: Q,K -> bf16, relayout [b][n][h][d] -> [b][h][n][d] ----------
__global__ __launch_bounds__(256) void convert_qk_kernel(
    const float* __restrict__ q, const float* __restrict__ k,
    __bf16* __restrict__ qb, __bf16* __restrict__ kb)
{
    const int is_k = blockIdx.y;
    const float* src = is_k ? k : q;
    __bf16* dst = is_k ? kb : qb;
    const float scale = is_k ? 1.0f : SCALE;

    int t = blockIdx.x * 256 + threadIdx.x;   // 524288 threads, 8 elems each
    int r = t >> 3;                           // source row (b,n,h), 0..65535
    int j = (t & 7) * 8;
    int b = r >> 15;                          // / (N*H)
    int rem = r & 32767;
    int n = rem >> 4;
    int h = rem & 15;

    const float* s = src + (size_t)r * D_ + j;
    f32x4 v0 = *(const f32x4*)s;
    f32x4 v1 = *(const f32x4*)(s + 4);
    bf16x8 o;
    #pragma unroll
    for (int e = 0; e < 4; ++e) { o[e] = (__bf16)(v0[e] * scale); o[4 + e] = (__bf16)(v1[e] * scale); }
    *(bf16x8*)(dst + ((size_t)(b * H_ + h) * N_ + n) * D_ + j) = o;
}

// ---------------- pass 1b: V -> bf16 transposed [b][h][d][n] ----------
__global__ __launch_bounds__(256) void transpose_v_kernel(
    const float* __restrict__ v, __bf16* __restrict__ vt)
{
    __shared__ float tile[64][65];
    const int n0 = blockIdx.x * 64;
    const int h  = blockIdx.y;
    const int b  = blockIdx.z;
    const int t  = threadIdx.x;

    const float* vp = v + (size_t)b * N_ * HD + (size_t)h * D_;
    #pragma unroll
    for (int rep = 0; rep < 4; ++rep) {
        int idx = rep * 256 + t;
        int i  = idx >> 4;
        int c4 = (idx & 15) * 4;
        f32x4 x = *(const f32x4*)(vp + (size_t)(n0 + i) * HD + c4);
        tile[i][c4] = x[0]; tile[i][c4 + 1] = x[1]; tile[i][c4 + 2] = x[2]; tile[i][c4 + 3] = x[3];
    }
    __syncthreads();
    __bf16* vtp = vt + ((size_t)(b * H_ + h) * D_) * N_ + n0;
    #pragma unroll
    for (int rep = 0; rep < 2; ++rep) {
        int idx = rep * 256 + t;
        int d  = idx >> 3;
        int s8 = (idx & 7) * 8;
        bf16x8 o;
        #pragma unroll
        for (int j = 0; j < 8; ++j) o[j] = (__bf16)tile[s8 + j][d];
        *(bf16x8*)(vtp + (size_t)d * N_ + s8) = o;
    }
}

// ---------------- main: flash attention, all-bf16 operands ----------
__global__ __launch_bounds__(256) void attn_fwd_v2(
    const __bf16* __restrict__ qb,   // [b][h][n][d], pre-scaled
    const __bf16* __restrict__ kb,   // [b][h][n][d]
    const __bf16* __restrict__ vt,   // [b][h][d][n]
    float* __restrict__ out)         // [b][n][h][d]
{
    const int tid  = threadIdx.x;
    const int lane = tid & 63;
    const int w    = tid >> 6;
    const int lo   = lane & 15;
    const int hi   = lane >> 4;

    // T1 bijective XCD swizzle: 512 blocks = 8 XCDs x 64; each XCD owns 4 (b,h)
    int bid = blockIdx.x;
    int wg  = (bid & 7) * 64 + (bid >> 3);
    int qt  = wg & 15;
    int bh  = wg >> 4;
    int h   = bh & 15;
    int b   = bh >> 4;

    __shared__ __align__(16) __bf16 p_lds[4][16][72];  // wave-private

    const size_t bh_off = ((size_t)b * H_ + h) * (size_t)(N_ * D_);
    const __bf16* qp = qb + bh_off;
    const __bf16* kp = kb + bh_off;
    const __bf16* vp = vt + bh_off;

    const int q0 = qt * QBLK + w * 32;   // this wave's 32 rows

    bf16x8 qa[2][2];
    #pragma unroll
    for (int rb = 0; rb < 2; ++rb)
        #pragma unroll
        for (int kk = 0; kk < 2; ++kk)
            qa[rb][kk] = *(const bf16x8*)(qp + (size_t)(q0 + rb * 16 + lo) * D_ + kk * 32 + hi * 8);

    float m[2][4], l[2][4];
    f32x4 o[2][4];
    #pragma unroll
    for (int rb = 0; rb < 2; ++rb)
        #pragma unroll
        for (int r = 0; r < 4; ++r) { m[rb][r] = -INFINITY; l[rb][r] = 0.f; }
    #pragma unroll
    for (int rb = 0; rb < 2; ++rb)
        #pragma unroll
        for (int f = 0; f < 4; ++f) o[rb][f] = (f32x4)0.f;

    for (int kv0 = 0; kv0 < N_; kv0 += KVBLK) {
        // K fragments (shared by both row-blocks): 8 x 16B loads
        bf16x8 kf[4][2];
        #pragma unroll
        for (int c = 0; c < 4; ++c)
            #pragma unroll
            for (int kk = 0; kk < 2; ++kk)
                kf[c][kk] = *(const bf16x8*)(kp + (size_t)(kv0 + c * 16 + lo) * D_ + kk * 32 + hi * 8);
        // V fragments: 8 x 16B loads (contiguous thanks to transposed layout)
        bf16x8 vf[4][2];
        #pragma unroll
        for (int f = 0; f < 4; ++f)
            #pragma unroll
            for (int s2 = 0; s2 < 2; ++s2)
                vf[f][s2] = *(const bf16x8*)(vp + (size_t)(f * 16 + lo) * N_ + kv0 + s2 * 32 + hi * 8);

        #pragma unroll
        for (int rb = 0; rb < 2; ++rb) {
            // S[16][64]
            f32x4 s[4];
            #pragma unroll
            for (int c = 0; c < 4; ++c) {
                s[c] = (f32x4)0.f;
                #pragma unroll
                for (int kk = 0; kk < 2; ++kk)
                    s[c] = __builtin_amdgcn_mfma_f32_16x16x32_bf16(qa[rb][kk], kf[c][kk], s[c], 0, 0, 0);
            }
            // online softmax; l kept as per-lane partial (deferred reduction)
            float alpha[4];
            #pragma unroll
            for (int r = 0; r < 4; ++r) {
                float t = fmaxf(fmaxf(s[0][r], s[1][r]), fmaxf(s[2][r], s[3][r]));
                #pragma unroll
                for (int msk = 1; msk <= 8; msk <<= 1)
                    t = fmaxf(t, __shfl_xor(t, msk, 64));
                float mn = fmaxf(m[rb][r], t);
                float a  = __expf(m[rb][r] - mn);
                alpha[r] = a; m[rb][r] = mn;
                float p0 = __expf(s[0][r] - mn);
                float p1 = __expf(s[1][r] - mn);
                float p2 = __expf(s[2][r] - mn);
                float p3 = __expf(s[3][r] - mn);
                l[rb][r] = l[rb][r] * a + (p0 + p1) + (p2 + p3);
                p_lds[w][hi * 4 + r][lo]      = (__bf16)p0;
                p_lds[w][hi * 4 + r][16 + lo] = (__bf16)p1;
                p_lds[w][hi * 4 + r][32 + lo] = (__bf16)p2;
                p_lds[w][hi * 4 + r][48 + lo] = (__bf16)p3;
            }
            #pragma unroll
            for (int f = 0; f < 4; ++f)
                #pragma unroll
                for (int r = 0; r < 4; ++r) o[rb][f][r] *= alpha[r];

            // wave-synchronous LDS transpose (in-order per-wave LDS pipe)
            __asm__ volatile("" ::: "memory");
            bf16x8 pa0 = *(const bf16x8*)&p_lds[w][lo][hi * 8];
            bf16x8 pa1 = *(const bf16x8*)&p_lds[w][lo][32 + hi * 8];
            __asm__ volatile("" ::: "memory");

            #pragma unroll
            for (int f = 0; f < 4; ++f) {
                o[rb][f] = __builtin_amdgcn_mfma_f32_16x16x32_bf16(pa0, vf[f][0], o[rb][f], 0, 0, 0);
                o[rb][f] = __builtin_amdgcn_mfma_f32_16x16x32_bf16(pa1, vf[f][1], o[rb][f], 0, 0, 0);
            }
        }
    }

    // epilogue: reduce deferred l across the 16-lane row group, scale, store
    float* op = out + (size_t)b * N_ * HD + (size_t)h * D_;
    #pragma unroll
    for (int rb = 0; rb < 2; ++rb)
        #pragma unroll
        for (int r = 0; r < 4; ++r) {
            float rs = l[rb][r];
            #pragma unroll
            for (int msk = 1; msk <= 8; msk <<= 1)
                rs += __shfl_xor(rs, msk, 64);
            float rinv = 1.f / rs;
            float* orow = op + (size_t)(q0 + rb * 16 + hi * 4 + r) * HD;
            #pragma unroll
            for (int f = 0; f < 4; ++f)
                orow[f * 16 + lo] = o[rb][f][r] * rinv;
        }
}

// ---------------- fallback (round-1 kernel) if workspace too small ----------
__global__ __launch_bounds__(256) void attn_fwd_v1(
    const float* __restrict__ q, const float* __restrict__ k,
    const float* __restrict__ v, float* __restrict__ out)
{
    const int tid  = threadIdx.x;
    const int lane = tid & 63;
    const int w    = tid >> 6;
    const int lo   = lane & 15;
    const int hi   = lane >> 4;
    const int qt   = blockIdx.x;
    const int h    = blockIdx.y;
    const int b    = blockIdx.z;

    __shared__ __align__(16) __bf16 p_lds[4][16][40];

    const size_t bh_off = (size_t)b * N_ * HD + (size_t)h * D_;
    const float* qp = q + bh_off;
    const float* kp = k + bh_off;
    const float* vp = v + bh_off;
    float*       op = out + bh_off;

    const int q0 = qt * 64 + w * 16;

    bf16x8 qa[2];
    {
        const float* qrow = qp + (size_t)(q0 + lo) * HD + hi * 8;
        #pragma unroll
        for (int kk = 0; kk < 2; ++kk)
            #pragma unroll
            for (int j = 0; j < 8; ++j)
                qa[kk][j] = (__bf16)(qrow[kk * 32 + j] * SCALE);
    }

    float m[4], l[4];
    f32x4 o[4];
    #pragma unroll
    for (int r = 0; r < 4; ++r) { m[r] = -INFINITY; l[r] = 0.f; }
    #pragma unroll
    for (int f = 0; f < 4; ++f) o[f] = (f32x4)0.f;

    for (int kv0 = 0; kv0 < N_; kv0 += 32) {
        f32x4 s[2];
        #pragma unroll
        for (int c = 0; c < 2; ++c) {
            s[c] = (f32x4)0.f;
            const float* krow = kp + (size_t)(kv0 + c * 16 + lo) * HD + hi * 8;
            #pragma unroll
            for (int kk = 0; kk < 2; ++kk) {
                bf16x8 kb;
                #pragma unroll
                for (int j = 0; j < 8; ++j) kb[j] = (__bf16)krow[kk * 32 + j];
                s[c] = __builtin_amdgcn_mfma_f32_16x16x32_bf16(qa[kk], kb, s[c], 0, 0, 0);
            }
        }
        float alpha[4], p0[4], p1[4];
        #pragma unroll
        for (int r = 0; r < 4; ++r) {
            float t = fmaxf(s[0][r], s[1][r]);
            #pragma unroll
            for (int msk = 1; msk <= 8; msk <<= 1) t = fmaxf(t, __shfl_xor(t, msk, 64));
            float mn = fmaxf(m[r], t);
            alpha[r] = __expf(m[r] - mn);
            p0[r] = __expf(s[0][r] - mn);
            p1[r] = __expf(s[1][r] - mn);
            float rs = p0[r] + p1[r];
            #pragma unroll
            for (int msk = 1; msk <= 8; msk <<= 1) rs += __shfl_xor(rs, msk, 64);
            l[r] = l[r] * alpha[r] + rs;
            m[r] = mn;
        }
        #pragma unroll
        for (int f = 0; f < 4; ++f)
            #pragma unroll
            for (int r = 0; r < 4; ++r) o[f][r] *= alpha[r];
        #pragma unroll
        for (int r = 0; r < 4; ++r) {
            p_lds[w][hi * 4 + r][lo]      = (__bf16)p0[r];
            p_lds[w][hi * 4 + r][16 + lo] = (__bf16)p1[r];
        }
        __syncthreads();
        bf16x8 pa = *(const bf16x8*)&p_lds[w][lo][hi * 8];
        #pragma unroll
        for (int f = 0; f < 4; ++f) {
            const float* vrow = vp + (size_t)(kv0 + hi * 8) * HD + f * 16 + lo;
            bf16x8 vb;
            #pragma unroll
            for (int j = 0; j < 8; ++j) vb[j] = (__bf16)vrow[(size_t)j * HD];
            o[f] = __builtin_amdgcn_mfma_f32_16x16x32_bf16(pa, vb, o[f], 0, 0, 0);
        }
        __syncthreads();
    }
    #pragma unroll
    for (int r = 0; r < 4; ++r) {
        float rinv = 1.f / l[r];
        float* orow = op + (size_t)(q0 + hi * 4 + r) * HD;
        #pragma unroll
        for (int f = 0; f < 4; ++f) orow[f * 16 + lo] = o[f][r] * rinv;
    }
}

extern "C" void kernel_launch(void* const* d_in, const int* in_sizes, int n_in,
                              void* d_out, int out_size, void* d_ws, size_t ws_size,
                              hipStream_t stream)
{
    const float* q = (const float*)d_in[0];
    const float* k = (const float*)d_in[1];
    const float* v = (const float*)d_in[2];
    float* out = (float*)d_out;

    if (ws_size >= 3 * CVT_SZ) {
        __bf16* qb = (__bf16*)d_ws;
        __bf16* kb = (__bf16*)((char*)d_ws + CVT_SZ);
        __bf16* vt = (__bf16*)((char*)d_ws + 2 * CVT_SZ);

        convert_qk_kernel<<<dim3(2048, 2), 256, 0, stream>>>(q, k, qb, kb);
        transpose_v_kernel<<<dim3(N_ / 64, H_, B_), 256, 0, stream>>>(v, vt);
        attn_fwd_v2<<<dim3(512), 256, 0, stream>>>(qb, kb, vt, out);
    } else {
        attn_fwd_v1<<<dim3(N_ / 64, H_, B_), 256, 0, stream>>>(q, k, v, out);
    }
}